// Round 10
// baseline (95.984 us; speedup 1.0000x reference)
//
#include <hip/hip_runtime.h>

// Problem constants
#define D_B 8
#define N_T 2048
#define NN  64
#define N_H 8
#define N_C 32   // u-chunks of 64
#define NP  72   // padded LDS row stride (bf16): 144 B rows, 16B-aligned, 2-way alias (free)
#define FSP 68   // fp32 diag staging row stride (floats): 272 B rows, 16B-aligned

typedef __bf16 bf16;
typedef bf16 bf16x8 __attribute__((ext_vector_type(8)));
typedef bf16 bf16x4 __attribute__((ext_vector_type(4)));
typedef float f32x4 __attribute__((ext_vector_type(4)));

static __device__ __forceinline__ f32x4 mfma16(bf16x8 a, bf16x8 b, f32x4 c) {
    // a_frag[j] = A[lane&15][(lane>>4)*8+j]; b_frag[j] = B[(lane>>4)*8+j][lane&15]
    // d[r] = D[(lane>>4)*4+r][lane&15]
    return __builtin_amdgcn_mfma_f32_16x16x32_bf16(a, b, c, 0, 0, 0);
}

static __device__ __forceinline__ bf16x8 ldcvt8(const float* p) {
    const f32x4 v0 = *(const f32x4*)p;
    const f32x4 v1 = *(const f32x4*)(p + 4);
    bf16x8 r;
#pragma unroll
    for (int k = 0; k < 4; k++) { r[k] = (bf16)v0[k]; r[4 + k] = (bf16)v1[k]; }
    return r;
}

static __device__ __forceinline__ bf16x8 cvt8(const f32x4 v0, const f32x4 v1) {
    bf16x8 r;
#pragma unroll
    for (int k = 0; k < 4; k++) { r[k] = (bf16)v0[k]; r[4 + k] = (bf16)v1[k]; }
    return r;
}

static __device__ __forceinline__ bf16x4 cvt4(const f32x4 v) {
    bf16x4 r;
#pragma unroll
    for (int k = 0; k < 4; k++) r[k] = (bf16)v[k];
    return r;
}

// ---------------------------------------------------------------------------
// K1 (R10, Gram): block (b,c,zz) = head pair {2zz,2zz+1}, DIAG PATH ONLY.
// The prefix-dG pipeline is replaced by the Gram identity
//   Gcum = sum_h Q_h * Cpre * E_h^T,  Cpre = sum_{chunks<c} r_c^T r_c,
// so k_dg emits only C_c (fp32, zz==0 block, 8 MFMAs) + diag partials.
// Per head: [stage Q/E from T14-prefetched regs] A [Qr,Er MFMA -> QT2 [u][i'],
// ET [i][u]] B [S = masked r.Qr^T -> Sw (Ql region, dead) -> same-wave read ->
// PV acc += S.Er] C.  3 barriers/head (was 4), no dG MFMAs, no QT slab
// round-trip, no dacc, no fold. 256 thr, 36.9 KB LDS -> 4 blocks/CU.
// Grid (D_B, N_C, 4): linear%8 = b (XCD-local). All fragment maps verbatim
// from the R3/R5-proven kernel.
// ---------------------------------------------------------------------------
__global__ __launch_bounds__(256, 4) void k_dg(
    const float* __restrict__ rp, const float* __restrict__ Qm,
    const float* __restrict__ Em,
    float* __restrict__ Cq, float* __restrict__ diagq)
{
    __shared__ __align__(16) char smem[4 * 64 * NP * 2];  // 36864 B
    bf16* Ql  = (bf16*)smem;       // Q_h [i'][j]; S2: per-wave S slabs
    bf16* El  = Ql + 64 * NP;      // E_h [i][j]
    bf16* QT2 = El + 64 * NP;      // Qr [u][i']; tail: rT [j][u] (zz==0)
    bf16* ET  = QT2 + 64 * NP;     // Er [i][u]
    float* fst = (float*)smem;     // tail fp32 diag staging 64xFSP (Ql+El)

    const int b = blockIdx.x, c = blockIdx.y, zz = blockIdx.z;
    const int tid = threadIdx.x;
    const int w = tid >> 6, l = tid & 63, q = l >> 4, l16 = l & 15;
    const int row = tid >> 2, col = (tid & 3) * 16;

    // T14 prefetch: both heads' Q/E tiles into regs
    const int h0 = zz * 2;
    const float* q0 = Qm + (size_t)h0 * 4096 + row * 64 + col;
    const float* e0 = Em + (size_t)h0 * 4096 + row * 64 + col;
    f32x4 qA[4], eA[4], qB[4], eB[4];
    qA[0] = *(const f32x4*)q0;       qA[1] = *(const f32x4*)(q0 + 4);
    qA[2] = *(const f32x4*)(q0 + 8); qA[3] = *(const f32x4*)(q0 + 12);
    eA[0] = *(const f32x4*)e0;       eA[1] = *(const f32x4*)(e0 + 4);
    eA[2] = *(const f32x4*)(e0 + 8); eA[3] = *(const f32x4*)(e0 + 12);

    // A-frags: r rows u = t = c*64 + w*16 + l16 (shared by Qr/Er/S paths)
    const float* rrow = rp + ((size_t)b * N_T + c * 64 + w * 16 + l16) * NN;
    const bf16x8 a0 = ldcvt8(rrow + q * 8);
    const bf16x8 a1 = ldcvt8(rrow + 32 + q * 8);

    f32x4 acc[4];
#pragma unroll
    for (int ns = 0; ns < 4; ns++) { f32x4 z = {0.f, 0.f, 0.f, 0.f}; acc[ns] = z; }

#pragma unroll
    for (int hh = 0; hh < 2; hh++) {
        // ---- S0: stage Ql/El from regs; issue 2nd head's loads (hh==0)
        if (hh == 0) {
            *(bf16x8*)&Ql[row * NP + col]     = cvt8(qA[0], qA[1]);
            *(bf16x8*)&Ql[row * NP + col + 8] = cvt8(qA[2], qA[3]);
            *(bf16x8*)&El[row * NP + col]     = cvt8(eA[0], eA[1]);
            *(bf16x8*)&El[row * NP + col + 8] = cvt8(eA[2], eA[3]);
            const float* q1 = q0 + 4096;
            const float* e1 = e0 + 4096;
            qB[0] = *(const f32x4*)q1;       qB[1] = *(const f32x4*)(q1 + 4);
            qB[2] = *(const f32x4*)(q1 + 8); qB[3] = *(const f32x4*)(q1 + 12);
            eB[0] = *(const f32x4*)e1;       eB[1] = *(const f32x4*)(e1 + 4);
            eB[2] = *(const f32x4*)(e1 + 8); eB[3] = *(const f32x4*)(e1 + 12);
        } else {
            *(bf16x8*)&Ql[row * NP + col]     = cvt8(qB[0], qB[1]);
            *(bf16x8*)&Ql[row * NP + col + 8] = cvt8(qB[2], qB[3]);
            *(bf16x8*)&El[row * NP + col]     = cvt8(eB[0], eB[1]);
            *(bf16x8*)&El[row * NP + col + 8] = cvt8(eB[2], eB[3]);
        }
        __syncthreads();  // A: Ql/El ready
        // ---- S1: Qr -> QT2 [u][i'], Er -> ET [i][u]
#pragma unroll
        for (int ns = 0; ns < 4; ns++) {
            bf16x8 b0 = *(const bf16x8*)&Ql[(ns * 16 + l16) * NP + q * 8];
            bf16x8 b1 = *(const bf16x8*)&Ql[(ns * 16 + l16) * NP + 32 + q * 8];
            f32x4 z = {0.f, 0.f, 0.f, 0.f};
            f32x4 s = mfma16(a0, b0, z);
            s = mfma16(a1, b1, s);
#pragma unroll
            for (int r = 0; r < 4; r++)
                QT2[(w * 16 + q * 4 + r) * NP + ns * 16 + l16] = (bf16)s[r];
            b0 = *(const bf16x8*)&El[(ns * 16 + l16) * NP + q * 8];
            b1 = *(const bf16x8*)&El[(ns * 16 + l16) * NP + 32 + q * 8];
            f32x4 s2 = mfma16(a0, b0, z);
            s2 = mfma16(a1, b1, s2);
            bf16x4 p;
#pragma unroll
            for (int r = 0; r < 4; r++) p[r] = (bf16)s2[r];
            *(bf16x4*)&ET[(ns * 16 + l16) * NP + w * 16 + q * 4] = p;  // [i][u]
        }
        __syncthreads();  // B: QT2/ET ready; Ql/El dead
        // ---- S2: diag S (masked) -> Sw (Ql region) -> same-wave read -> PV
        {
            bf16* Sw = Ql + (w * 16) * NP;   // this wave's 16-row slab
#pragma unroll
            for (int nu = 0; nu < 4; nu++) {
                if (nu <= w) {
                    const bf16x8 b0 = *(const bf16x8*)&QT2[(nu * 16 + l16) * NP + q * 8];
                    const bf16x8 b1 = *(const bf16x8*)&QT2[(nu * 16 + l16) * NP + 32 + q * 8];
                    f32x4 z = {0.f, 0.f, 0.f, 0.f};
                    f32x4 sv = mfma16(a0, b0, z);
                    sv = mfma16(a1, b1, sv);
                    const int u_loc = nu * 16 + l16;
#pragma unroll
                    for (int r = 0; r < 4; r++) {
                        const int t_loc = w * 16 + q * 4 + r;
                        Sw[(q * 4 + r) * NP + u_loc] = (u_loc <= t_loc) ? (bf16)sv[r] : (bf16)0.f;
                    }
                } else if ((w == 0 && nu == 1) || (w == 2 && nu == 3)) {
#pragma unroll
                    for (int r = 0; r < 4; r++)
                        Sw[(q * 4 + r) * NP + nu * 16 + l16] = (bf16)0.f;
                }
            }
            const bf16x8 sa0 = *(const bf16x8*)&Sw[l16 * NP + q * 8];
#pragma unroll
            for (int ns = 0; ns < 4; ns++) {
                const bf16x8 e0 = *(const bf16x8*)&ET[(ns * 16 + l16) * NP + q * 8];
                acc[ns] = mfma16(sa0, e0, acc[ns]);
            }
            if (w >= 2) {
                const bf16x8 sa1 = *(const bf16x8*)&Sw[l16 * NP + 32 + q * 8];
#pragma unroll
                for (int ns = 0; ns < 4; ns++) {
                    const bf16x8 e1 = *(const bf16x8*)&ET[(ns * 16 + l16) * NP + 32 + q * 8];
                    acc[ns] = mfma16(sa1, e1, acc[ns]);
                }
            }
        }
        __syncthreads();  // C: end of head (slabs reused next head)
    }

    // ---- tail: diag -> fst (fp32); zz==0: rT [j][u] -> QT2 region
#pragma unroll
    for (int ns = 0; ns < 4; ns++)
#pragma unroll
        for (int r = 0; r < 4; r++)
            fst[(w * 16 + q * 4 + r) * FSP + ns * 16 + l16] = acc[ns][r];
    if (zz == 0) {
        bf16* rT = QT2;
#pragma unroll
        for (int jj = 0; jj < 8; jj++) {
            rT[(q * 8 + jj) * NP + w * 16 + l16]      = a0[jj];
            rT[(32 + q * 8 + jj) * NP + w * 16 + l16] = a1[jj];
        }
    }
    __syncthreads();
    // diag flush (4 streams, proven addressing)
    {
        float* dd = diagq + (((size_t)(b * N_C + c)) * 4 + zz) * 4096 + row * 64 + col;
#pragma unroll
        for (int k = 0; k < 4; k++)
            *(f32x4*)(dd + k * 4) = *(const f32x4*)&fst[row * FSP + col + k * 4];
    }
    // C_c = r^T r (zz==0): wave w = j-block; symmetric; store fp32 [j][j']
    if (zz == 0) {
        const bf16* rT = QT2;
        const bf16x8 aQ0 = *(const bf16x8*)&rT[(w * 16 + l16) * NP + q * 8];
        const bf16x8 aQ1 = *(const bf16x8*)&rT[(w * 16 + l16) * NP + 32 + q * 8];
        float* cdst = Cq + (size_t)(b * N_C + c) * 4096;
#pragma unroll
        for (int nb = 0; nb < 4; nb++) {
            const bf16x8 bQ0 = *(const bf16x8*)&rT[(nb * 16 + l16) * NP + q * 8];
            const bf16x8 bQ1 = *(const bf16x8*)&rT[(nb * 16 + l16) * NP + 32 + q * 8];
            f32x4 z = {0.f, 0.f, 0.f, 0.f};
            f32x4 cc = mfma16(aQ0, bQ0, z);
            cc = mfma16(aQ1, bQ1, cc);
#pragma unroll
            for (int r = 0; r < 4; r++)
                cdst[(w * 16 + q * 4 + r) * 64 + nb * 16 + l16] = cc[r];
        }
    }
}

// ---------------------------------------------------------------------------
// K2 (R10, Gram): grid (D_B, N_C) x 1024 thr. Phase 0: scan Cq (fp32,
// 1 stream, t<c) -> Cb bf16; stage head0 Q/E; hoist ra/dsum. Phase 1 (8
// heads, T14 ping-pong staging): wave (mb=wv&3, nb=wv>>2):
//   S1: T2 = Q_h . Cpre  (A = Ql rows; B = Cb rows via SYMMETRY) -> T2s [i'][j]
//   S2: gacc += E-form:  Gm tile += T2 . E_h^T (A = T2s rows, B = El rows)
// Phase 2: Gb[i][i'] = Gm (reuse Cb slab). Phase 3: out = r_t.Gb + diag
// (R8-proven epilogue, wave (qq=wv>>2, ib=wv&3)). 55 KB LDS, 1 block/CU.
// Grid linear %8 = b (XCD-local; Cq/diagq/Qm/Em L2-warm from k_dg).
// ---------------------------------------------------------------------------
__global__ __launch_bounds__(1024, 4) void k_out(
    const float* __restrict__ rp, const float* __restrict__ Cq,
    const float* __restrict__ Qm, const float* __restrict__ Em,
    const float* __restrict__ diagq, float* __restrict__ out)
{
    __shared__ __align__(16) bf16 QlA[64 * NP];
    __shared__ __align__(16) bf16 ElA[64 * NP];
    __shared__ __align__(16) bf16 QlB[64 * NP];
    __shared__ __align__(16) bf16 ElB[64 * NP];
    __shared__ __align__(16) bf16 Cb[64 * NP];    // Cpre bf16; later Gb [i][i']
    __shared__ __align__(16) bf16 T2s[64 * NP];   // T2 [i'][j]
    const int b = blockIdx.x, c = blockIdx.y;
    const int tid = threadIdx.x;
    const int wv = tid >> 6, ln = tid & 63, q = ln >> 4, l16 = ln & 15;
    const int mb = wv & 3, nb = wv >> 2;   // phase-1 tile roles
    const int qq = wv >> 2, ib = wv & 3;   // phase-3 roles (R8-proven)
    const int srow = tid >> 4, scol = (tid & 15) * 4;  // staging: 4 elems/thread

    // A-frags for epilogue: r rows t = c*64 + qq*16 + l16
    const float* rr = rp + ((size_t)b * N_T + c * 64 + qq * 16 + l16) * NN;
    const bf16x8 ra0 = ldcvt8(rr + q * 8);
    const bf16x8 ra1 = ldcvt8(rr + 32 + q * 8);

    // diag fold: 4 fp32 streams
    float dsum[4];
#pragma unroll
    for (int r = 0; r < 4; r++) {
        const size_t di = (((size_t)(b * N_C + c)) * 4) * 4096 +
                          (qq * 16 + q * 4 + r) * 64 + ib * 16 + l16;
        dsum[r] = diagq[di] + diagq[di + 4096] + diagq[di + 2 * 4096] + diagq[di + 3 * 4096];
    }

    // T14: prefetch heads 0,1 Q/E (1 f32x4 each per matrix per thread)
    f32x4 qpf[2], epf[2];
    qpf[0] = *(const f32x4*)(Qm + srow * 64 + scol);
    epf[0] = *(const f32x4*)(Em + srow * 64 + scol);
    qpf[1] = *(const f32x4*)(Qm + 4096 + srow * 64 + scol);
    epf[1] = *(const f32x4*)(Em + 4096 + srow * 64 + scol);

    // scan Cq (fp32, 1 stream) for t<c; 4 elems/thread, batch-4
    float run[4];
#pragma unroll
    for (int k = 0; k < 4; k++) run[k] = 0.f;
    {
        const float* base = Cq + (size_t)b * N_C * 4096 + tid * 4;
        int t = 0;
        for (; t + 4 <= c; t += 4) {
            f32x4 v[4];
#pragma unroll
            for (int j = 0; j < 4; j++) v[j] = *(const f32x4*)(base + (size_t)(t + j) * 4096);
#pragma unroll
            for (int j = 0; j < 4; j++)
#pragma unroll
                for (int k = 0; k < 4; k++) run[k] += v[j][k];
        }
        for (; t < c; t++) {
            const f32x4 v0 = *(const f32x4*)(base + (size_t)t * 4096);
#pragma unroll
            for (int k = 0; k < 4; k++) run[k] += v0[k];
        }
    }
    {
        bf16x4 o;
#pragma unroll
        for (int k = 0; k < 4; k++) o[k] = (bf16)run[k];
        *(bf16x4*)&Cb[srow * NP + scol] = o;      // Cpre [j][j'] bf16 (symmetric)
    }
    // stage head 0
    *(bf16x4*)&QlA[srow * NP + scol] = cvt4(qpf[0]);
    *(bf16x4*)&ElA[srow * NP + scol] = cvt4(epf[0]);
    __syncthreads();  // Cb + head0 slabs ready

    // ---- phase 1: 8 heads, gacc = Gm tile (mb, nb) accumulated over h
    f32x4 gacc = {0.f, 0.f, 0.f, 0.f};
#pragma unroll
    for (int h = 0; h < 8; h++) {
        bf16* Qc = (h & 1) ? QlB : QlA;
        bf16* Ec = (h & 1) ? ElB : ElA;
        bf16* Qn = (h & 1) ? QlA : QlB;
        bf16* En = (h & 1) ? ElA : ElB;
        // S1: T2 tile = Q_h . Cpre   (B via symmetry: Cpre[j',j] = Cpre[j,j'])
        {
            const bf16x8 aq0 = *(const bf16x8*)&Qc[(mb * 16 + l16) * NP + q * 8];
            const bf16x8 aq1 = *(const bf16x8*)&Qc[(mb * 16 + l16) * NP + 32 + q * 8];
            const bf16x8 cb0 = *(const bf16x8*)&Cb[(nb * 16 + l16) * NP + q * 8];
            const bf16x8 cb1 = *(const bf16x8*)&Cb[(nb * 16 + l16) * NP + 32 + q * 8];
            f32x4 z = {0.f, 0.f, 0.f, 0.f};
            f32x4 t2 = mfma16(aq0, cb0, z);
            t2 = mfma16(aq1, cb1, t2);
#pragma unroll
            for (int r = 0; r < 4; r++)
                T2s[(mb * 16 + q * 4 + r) * NP + nb * 16 + l16] = (bf16)t2[r];
        }
        // stage h+1 (slabs Qn/En dead since S2_{h-1} barrier); issue h+2 loads
        if (h < 7) {
            *(bf16x4*)&Qn[srow * NP + scol] = cvt4(qpf[(h + 1) & 1]);
            *(bf16x4*)&En[srow * NP + scol] = cvt4(epf[(h + 1) & 1]);
        }
        if (h < 6) {
            qpf[h & 1] = *(const f32x4*)(Qm + (size_t)(h + 2) * 4096 + srow * 64 + scol);
            epf[h & 1] = *(const f32x4*)(Em + (size_t)(h + 2) * 4096 + srow * 64 + scol);
        }
        __syncthreads();  // T2s ready
        // S2: gacc += T2 . E_h^T
        {
            const bf16x8 at0 = *(const bf16x8*)&T2s[(mb * 16 + l16) * NP + q * 8];
            const bf16x8 at1 = *(const bf16x8*)&T2s[(mb * 16 + l16) * NP + 32 + q * 8];
            const bf16x8 be0 = *(const bf16x8*)&Ec[(nb * 16 + l16) * NP + q * 8];
            const bf16x8 be1 = *(const bf16x8*)&Ec[(nb * 16 + l16) * NP + 32 + q * 8];
            gacc = mfma16(at0, be0, gacc);
            gacc = mfma16(at1, be1, gacc);
        }
        __syncthreads();  // Ec/T2s consumed; next head may overwrite
    }

    // ---- phase 2: Gb[i][i'] = Gm[i',i]  (reuse Cb slab; D: m=i', n=i)
    *(bf16x4*)&Cb[(nb * 16 + l16) * NP + mb * 16 + q * 4] = cvt4(gacc);
    __syncthreads();

    // ---- phase 3: out = r_t . Gcum + diag (R8-proven epilogue)
    f32x4 pacc = {0.f, 0.f, 0.f, 0.f};
    const bf16x8 g0 = *(const bf16x8*)&Cb[(ib * 16 + l16) * NP + q * 8];
    const bf16x8 g1 = *(const bf16x8*)&Cb[(ib * 16 + l16) * NP + 32 + q * 8];
    pacc = mfma16(ra0, g0, pacc);
    pacc = mfma16(ra1, g1, pacc);
#pragma unroll
    for (int r = 0; r < 4; r++)
        out[((size_t)b * N_T + c * 64 + qq * 16 + q * 4 + r) * NN + ib * 16 + l16] =
            pacc[r] + dsum[r];
}

// ---------------------------------------------------------------------------
extern "C" void kernel_launch(void* const* d_in, const int* in_sizes, int n_in,
                              void* d_out, int out_size, void* d_ws, size_t ws_size,
                              hipStream_t stream) {
    const float* rp = (const float*)d_in[0];   // (8, 2048, 64) fp32
    const float* Qm = (const float*)d_in[1];   // (8, 64, 64)
    const float* Em = (const float*)d_in[2];   // (8, 64, 64)
    float* out = (float*)d_out;                // (8, 2048, 64) fp32

    // ws: Cq 4.2 MB (fp32 Gram) + diagq 16.8 MB (fp32, 4 partials)
    float* Cq = (float*)d_ws;
    float* diagq = Cq + (size_t)D_B * N_C * 4096;

    k_dg<<<dim3(D_B, N_C, 4), 256, 0, stream>>>(rp, Qm, Em, Cq, diagq);
    k_out<<<dim3(D_B, N_C), 1024, 0, stream>>>(rp, Cq, Qm, Em, diagq, out);
}

// Round 11
// 89.299 us; speedup vs baseline: 1.0749x; 1.0749x over previous
//
#include <hip/hip_runtime.h>

// Problem constants
#define D_B 8
#define N_T 2048
#define NN  64
#define N_H 8
#define N_C 32   // u-chunks of 64
#define NP  72   // padded LDS row stride (bf16): 144 B rows, 16B-aligned, 2-way alias (free)
#define FSP 68   // fp32 diag staging row stride (floats): 272 B rows, 16B-aligned

typedef __bf16 bf16;
typedef bf16 bf16x8 __attribute__((ext_vector_type(8)));
typedef bf16 bf16x4 __attribute__((ext_vector_type(4)));
typedef float f32x4 __attribute__((ext_vector_type(4)));

static __device__ __forceinline__ f32x4 mfma16(bf16x8 a, bf16x8 b, f32x4 c) {
    // a_frag[j] = A[lane&15][(lane>>4)*8+j]; b_frag[j] = B[(lane>>4)*8+j][lane&15]
    // d[r] = D[(lane>>4)*4+r][lane&15]
    return __builtin_amdgcn_mfma_f32_16x16x32_bf16(a, b, c, 0, 0, 0);
}

static __device__ __forceinline__ bf16x8 ldcvt8(const float* p) {
    const f32x4 v0 = *(const f32x4*)p;
    const f32x4 v1 = *(const f32x4*)(p + 4);
    bf16x8 r;
#pragma unroll
    for (int k = 0; k < 4; k++) { r[k] = (bf16)v0[k]; r[4 + k] = (bf16)v1[k]; }
    return r;
}

// cvt 2 prefetched f32x4 regs -> bf16x8 (identical numerics to ldcvt8)
static __device__ __forceinline__ bf16x8 cvt8(const f32x4 v0, const f32x4 v1) {
    bf16x8 r;
#pragma unroll
    for (int k = 0; k < 4; k++) { r[k] = (bf16)v0[k]; r[4 + k] = (bf16)v1[k]; }
    return r;
}

// ---------------------------------------------------------------------------
// One head of the R5-proven k_dg pipeline, with T14 async-STAGE:
//   stage Ql/El from PRE-LOADED regs (no vmcnt on critical path), issue the
//   NEXT head's global loads (regs), then A;Qr/Er;B;dG+QT2;C;diag+PV;D.
// All MFMA fragment maps verbatim from the R3/R5-proven kernel.
// ---------------------------------------------------------------------------
template <bool LAST>
static __device__ __forceinline__ void head_body(
    bf16* __restrict__ Ql, bf16* __restrict__ El,
    bf16* __restrict__ QT, bf16* __restrict__ ET,
    const bf16x8 a0, const bf16x8 a1,
    const f32x4 (&qpre)[4], const f32x4 (&epre)[4],
    const float* qnext, const float* enext,
    f32x4 (&qpre2)[4], f32x4 (&epre2)[4],
    int w, int q, int l16, int row, int col,
    f32x4 (&dacc)[4], f32x4 (&acc)[4])
{
    // ---- stage from regs (pure cvt + ds_write)
    *(bf16x8*)&Ql[row * NP + col]     = cvt8(qpre[0], qpre[1]);
    *(bf16x8*)&Ql[row * NP + col + 8] = cvt8(qpre[2], qpre[3]);
    *(bf16x8*)&El[row * NP + col]     = cvt8(epre[0], epre[1]);
    *(bf16x8*)&El[row * NP + col + 8] = cvt8(epre[2], epre[3]);
    // ---- issue next head's loads (hidden under segments A..D)
    if (!LAST) {
        qpre2[0] = *(const f32x4*)qnext;       qpre2[1] = *(const f32x4*)(qnext + 4);
        qpre2[2] = *(const f32x4*)(qnext + 8); qpre2[3] = *(const f32x4*)(qnext + 12);
        epre2[0] = *(const f32x4*)enext;       epre2[1] = *(const f32x4*)(enext + 4);
        epre2[2] = *(const f32x4*)(enext + 8); epre2[3] = *(const f32x4*)(enext + 12);
    }
    __syncthreads();  // A: Ql/El ready
    // ---- Qr, Er for this wave's 16 u-rows; keep Qr bf16 in regs (pq)
    bf16x4 pq[4];
#pragma unroll
    for (int ns = 0; ns < 4; ns++) {
        bf16x8 b0 = *(const bf16x8*)&Ql[(ns * 16 + l16) * NP + q * 8];
        bf16x8 b1 = *(const bf16x8*)&Ql[(ns * 16 + l16) * NP + 32 + q * 8];
        f32x4 z = {0.f, 0.f, 0.f, 0.f};
        f32x4 s = mfma16(a0, b0, z);
        s = mfma16(a1, b1, s);
        bf16x4 p;
#pragma unroll
        for (int r = 0; r < 4; r++) p[r] = (bf16)s[r];
        pq[ns] = p;
        *(bf16x4*)&QT[(ns * 16 + l16) * NP + w * 16 + q * 4] = p;  // [i'][u]
        b0 = *(const bf16x8*)&El[(ns * 16 + l16) * NP + q * 8];
        b1 = *(const bf16x8*)&El[(ns * 16 + l16) * NP + 32 + q * 8];
        f32x4 s2 = mfma16(a0, b0, z);
        s2 = mfma16(a1, b1, s2);
#pragma unroll
        for (int r = 0; r < 4; r++) p[r] = (bf16)s2[r];
        *(bf16x4*)&ET[(ns * 16 + l16) * NP + w * 16 + q * 4] = p;  // [i][u]
    }
    __syncthreads();  // B: QT/ET ready; Ql/El now dead
    // ---- dG += Qr^T.Er; in parallel write QT2 [u][i'] -> Ql
    {
        const bf16x8 qa0 = *(const bf16x8*)&QT[(w * 16 + l16) * NP + q * 8];
        const bf16x8 qa1 = *(const bf16x8*)&QT[(w * 16 + l16) * NP + 32 + q * 8];
#pragma unroll
        for (int ns = 0; ns < 4; ns++) {
            const bf16x8 e0 = *(const bf16x8*)&ET[(ns * 16 + l16) * NP + q * 8];
            const bf16x8 e1 = *(const bf16x8*)&ET[(ns * 16 + l16) * NP + 32 + q * 8];
            dacc[ns] = mfma16(qa0, e0, dacc[ns]);
            dacc[ns] = mfma16(qa1, e1, dacc[ns]);
        }
    }
#pragma unroll
    for (int ns = 0; ns < 4; ns++)
#pragma unroll
        for (int r = 0; r < 4; r++)
            Ql[(w * 16 + q * 4 + r) * NP + ns * 16 + l16] = pq[ns][r];
    __syncthreads();  // C: QT2 (Ql) ready; El dead -> per-wave S slabs
    // ---- diag: S[t][u] = mask(r_t . Qr_u^T); only nu <= w nonzero
    {
        bf16* Sw = El + (w * 16) * NP;   // this wave's 16-row slab
#pragma unroll
        for (int nu = 0; nu < 4; nu++) {
            if (nu <= w) {
                const bf16x8 b0 = *(const bf16x8*)&Ql[(nu * 16 + l16) * NP + q * 8];
                const bf16x8 b1 = *(const bf16x8*)&Ql[(nu * 16 + l16) * NP + 32 + q * 8];
                f32x4 z = {0.f, 0.f, 0.f, 0.f};
                f32x4 sv = mfma16(a0, b0, z);
                sv = mfma16(a1, b1, sv);
                const int u_loc = nu * 16 + l16;
#pragma unroll
                for (int r = 0; r < 4; r++) {
                    const int t_loc = w * 16 + q * 4 + r;
                    Sw[(q * 4 + r) * NP + u_loc] = (u_loc <= t_loc) ? (bf16)sv[r] : (bf16)0.f;
                }
            } else if ((w == 0 && nu == 1) || (w == 2 && nu == 3)) {
#pragma unroll
                for (int r = 0; r < 4; r++)
                    Sw[(q * 4 + r) * NP + nu * 16 + l16] = (bf16)0.f;
            }
        }
        // same-wave in-order DS read-back; PV: acc += S.Er
        const bf16x8 sa0 = *(const bf16x8*)&Sw[l16 * NP + q * 8];
#pragma unroll
        for (int ns = 0; ns < 4; ns++) {
            const bf16x8 e0 = *(const bf16x8*)&ET[(ns * 16 + l16) * NP + q * 8];
            acc[ns] = mfma16(sa0, e0, acc[ns]);
        }
        if (w >= 2) {
            const bf16x8 sa1 = *(const bf16x8*)&Sw[l16 * NP + 32 + q * 8];
#pragma unroll
            for (int ns = 0; ns < 4; ns++) {
                const bf16x8 e1 = *(const bf16x8*)&ET[(ns * 16 + l16) * NP + 32 + q * 8];
                acc[ns] = mfma16(sa1, e1, acc[ns]);
            }
        }
    }
    __syncthreads();  // D: end of head (Ql/El/QT/ET reused next iter)
}

// ---------------------------------------------------------------------------
// K1 (R8-proven, 88.8 µs config): 512 threads = two independent 4-wave
// groups, each the proven 2-head pipeline on its own 36.9 KB LDS slab set;
// head Q/E tiles register-prefetched (T14). Cross-group fp32 fold -> dGh
// (bf16, 2 partials) + diagh (fp32, 2 partials). LDS 73.7 KB -> 2 blocks/CU.
// Grid (D_B, N_C, 2): linear%8 = b (XCD-local).
// ---------------------------------------------------------------------------
__global__ __launch_bounds__(512, 4) void k_dg(
    const float* __restrict__ rp, const float* __restrict__ Qm,
    const float* __restrict__ Em,
    bf16* __restrict__ dGh, float* __restrict__ diagh)
{
    __shared__ __align__(16) char smem[2 * 4 * 64 * NP * 2];  // 73728 B
    const int b = blockIdx.x, c = blockIdx.y, zz = blockIdx.z;
    const int tid = threadIdx.x;
    const int g = tid >> 8, t8 = tid & 255;          // group, within-group tid
    bf16* Ql = (bf16*)smem + (size_t)g * 4 * 64 * NP;  // Q_h [i'][j]; later QT2 [u][i']
    bf16* El = Ql + 64 * NP;                           // E_h [i][j]; later S slabs
    bf16* QT = El + 64 * NP;                           // Qr [i'][u]; dG staging at tail
    bf16* ET = QT + 64 * NP;                           // Er [i][u]
    float* fst = (float*)Ql;                           // tail fp32 diag 64xFSP (Ql+El)

    const int w = t8 >> 6, l = t8 & 63, q = l >> 4, l16 = l & 15;
    const int row = t8 >> 2, col = (t8 & 3) * 16;

    // first head's Q/E prefetch + A-frag loads issue together
    const int h0 = zz * 4 + g * 2;
    const float* q0 = Qm + (size_t)h0 * 4096 + row * 64 + col;
    const float* e0 = Em + (size_t)h0 * 4096 + row * 64 + col;
    f32x4 qA[4], eA[4], qB[4], eB[4];
    qA[0] = *(const f32x4*)q0;       qA[1] = *(const f32x4*)(q0 + 4);
    qA[2] = *(const f32x4*)(q0 + 8); qA[3] = *(const f32x4*)(q0 + 12);
    eA[0] = *(const f32x4*)e0;       eA[1] = *(const f32x4*)(e0 + 4);
    eA[2] = *(const f32x4*)(e0 + 8); eA[3] = *(const f32x4*)(e0 + 12);

    // A-frags: r' rows u = t = c*64 + w*16 + l16 (shared by Qr/Er/S paths)
    const float* rrow = rp + ((size_t)b * N_T + c * 64 + w * 16 + l16) * NN;
    const bf16x8 a0 = ldcvt8(rrow + q * 8);
    const bf16x8 a1 = ldcvt8(rrow + 32 + q * 8);

    f32x4 dacc[4], acc[4];
#pragma unroll
    for (int ns = 0; ns < 4; ns++) {
        f32x4 z = {0.f, 0.f, 0.f, 0.f};
        dacc[ns] = z; acc[ns] = z;
    }

    head_body<false>(Ql, El, QT, ET, a0, a1, qA, eA,
                     q0 + 4096, e0 + 4096, qB, eB,
                     w, q, l16, row, col, dacc, acc);
    head_body<true>(Ql, El, QT, ET, a0, a1, qB, eB,
                    nullptr, nullptr, qA, eA,
                    w, q, l16, row, col, dacc, acc);

    // ---- tail: per-group stage dG (bf16 [i][i'] -> QT) and diag (fp32 -> fst)
#pragma unroll
    for (int ns = 0; ns < 4; ns++) {
        bf16x4 p;
#pragma unroll
        for (int r = 0; r < 4; r++) p[r] = (bf16)dacc[ns][r];
        *(bf16x4*)&QT[(ns * 16 + l16) * NP + w * 16 + q * 4] = p;
    }
#pragma unroll
    for (int ns = 0; ns < 4; ns++)
#pragma unroll
        for (int r = 0; r < 4; r++)
            fst[(w * 16 + q * 4 + r) * FSP + ns * 16 + l16] = acc[ns][r];
    __syncthreads();
    // ---- cross-group fold (all 512 threads; 8 elems each) -> dGh, diagh
    {
        const int rr2 = tid >> 3, cc2 = (tid & 7) * 8;
        const bf16* QT0 = (const bf16*)smem + 2 * 64 * NP;
        const bf16* QT1 = (const bf16*)smem + 4 * 64 * NP + 2 * 64 * NP;
        const float* f0 = (const float*)smem;
        const float* f1 = (const float*)((const bf16*)smem + 4 * 64 * NP);
        const bf16x8 d0 = *(const bf16x8*)&QT0[rr2 * NP + cc2];
        const bf16x8 d1 = *(const bf16x8*)&QT1[rr2 * NP + cc2];
        bf16x8 o;
#pragma unroll
        for (int k = 0; k < 8; k++) o[k] = (bf16)((float)d0[k] + (float)d1[k]);
        const size_t tb = (((size_t)(b * N_C + c)) * 2 + zz) * 4096 + rr2 * 64 + cc2;
        *(bf16x8*)(dGh + tb) = o;
        float ds[8];
#pragma unroll
        for (int k = 0; k < 8; k++)
            ds[k] = f0[rr2 * FSP + cc2 + k] + f1[rr2 * FSP + cc2 + k];
        *(f32x4*)(diagh + tb)     = *(const f32x4*)&ds[0];
        *(f32x4*)(diagh + tb + 4) = *(const f32x4*)&ds[4];
    }
}

// ---------------------------------------------------------------------------
// K2 (R8-proven): grid (D_B, N_C) x 1024 threads — the 4 zz quarters of a
// (b,c) SHARE one block, so the dGh prefix scan runs ONCE per (b,c) instead
// of 4x. Scan: 1024 threads x 4 elems (bf16x4), 8 loads in flight. Epilogue
// per wave (R6-validated mapping): wave wv -> quarter wv>>2, i-block wv&3;
// 2 prefix MFMAs + fp32 diag fold + store. 9.2 KB LDS. Grid %8 = b.
// ---------------------------------------------------------------------------
__global__ __launch_bounds__(1024, 4) void k_out(
    const float* __restrict__ rp, const bf16* __restrict__ dGh,
    const float* __restrict__ diagh, float* __restrict__ out)
{
    __shared__ bf16 Gb[64 * NP];   // Gcum [i][i'] bf16
    const int b = blockIdx.x, c = blockIdx.y;
    const int tid = threadIdx.x;
    const int wv = tid >> 6, ln = tid & 63, q = ln >> 4, l16 = ln & 15;
    const int qq = wv >> 2, ib = wv & 3;   // quarter, i-block

    // A-frags (hoisted): r' rows t = c*64 + qq*16 + l16 (fp32, L2/L3-resident)
    const float* rr = rp + ((size_t)b * N_T + c * 64 + qq * 16 + l16) * NN;
    const bf16x8 ra0 = ldcvt8(rr + q * 8);
    const bf16x8 ra1 = ldcvt8(rr + 32 + q * 8);

    // diag fold (fp32, hoisted): wave (qq, ib); 2 partials
    float dsum[4];
#pragma unroll
    for (int r = 0; r < 4; r++) {
        const size_t di = (((size_t)(b * N_C + c)) * 2) * 4096 +
                          (qq * 16 + q * 4 + r) * 64 + ib * 16 + l16;
        dsum[r] = diagh[di] + diagh[di + 4096];
    }

    // register scan of the 2 dGh streams for t<c; 4 elems/thread, batch-8
    float run[4];
#pragma unroll
    for (int k = 0; k < 4; k++) run[k] = 0.f;
    {
        const bf16* base = dGh + (size_t)b * N_C * 2 * 4096 + tid * 4;
        int t = 0;
        for (; t + 4 <= c; t += 4) {
            bf16x4 v[8];
#pragma unroll
            for (int j = 0; j < 8; j++) {   // j = (t-offset<<1)|partial
                const size_t off = (size_t)((t + (j >> 1)) * 2 + (j & 1)) * 4096;
                v[j] = *(const bf16x4*)(base + off);
            }
#pragma unroll
            for (int j = 0; j < 8; j++)
#pragma unroll
                for (int k = 0; k < 4; k++) run[k] += (float)v[j][k];
        }
        for (; t < c; t++) {
#pragma unroll
            for (int p = 0; p < 2; p++) {
                const bf16x4 v0 = *(const bf16x4*)(base + (size_t)(t * 2 + p) * 4096);
#pragma unroll
                for (int k = 0; k < 4; k++) run[k] += (float)v0[k];
            }
        }
    }
    // Gb publish: elem e = tid*4+k -> row e>>6 = tid>>4, col (tid&15)*4 + k
    {
        bf16x4 o;
#pragma unroll
        for (int k = 0; k < 4; k++) o[k] = (bf16)run[k];
        *(bf16x4*)&Gb[(tid >> 4) * NP + (tid & 15) * 4] = o;
    }
    __syncthreads();  // Gb ready
    f32x4 pacc = {0.f, 0.f, 0.f, 0.f};
    const bf16x8 g0 = *(const bf16x8*)&Gb[(ib * 16 + l16) * NP + q * 8];
    const bf16x8 g1 = *(const bf16x8*)&Gb[(ib * 16 + l16) * NP + 32 + q * 8];
    pacc = mfma16(ra0, g0, pacc);
    pacc = mfma16(ra1, g1, pacc);
#pragma unroll
    for (int r = 0; r < 4; r++)
        out[((size_t)b * N_T + c * 64 + qq * 16 + q * 4 + r) * NN + ib * 16 + l16] =
            pacc[r] + dsum[r];
}

// ---------------------------------------------------------------------------
extern "C" void kernel_launch(void* const* d_in, const int* in_sizes, int n_in,
                              void* d_out, int out_size, void* d_ws, size_t ws_size,
                              hipStream_t stream) {
    const float* rp = (const float*)d_in[0];   // (8, 2048, 64) fp32
    const float* Qm = (const float*)d_in[1];   // (8, 64, 64)
    const float* Em = (const float*)d_in[2];   // (8, 64, 64)
    float* out = (float*)d_out;                // (8, 2048, 64) fp32

    // ws: dGh 4.2 MB (bf16, 2 partials) + diagh 8.4 MB (fp32, 2 partials)
    bf16* dGh = (bf16*)d_ws;
    float* diagh = (float*)(dGh + (size_t)D_B * N_C * 2 * 4096);

    k_dg<<<dim3(D_B, N_C, 2), 512, 0, stream>>>(rp, Qm, Em, dGh, diagh);
    k_out<<<dim3(D_B, N_C), 1024, 0, stream>>>(rp, dGh, diagh, out);
}